// Round 1
// baseline (1291.073 us; speedup 1.0000x reference)
//
#include <hip/hip_runtime.h>
#include <stdint.h>

typedef unsigned short u16;
typedef __attribute__((ext_vector_type(8))) short v8s;   // 8 x bf16 (as raw shorts)
typedef __attribute__((ext_vector_type(4))) float v4f;   // MFMA accumulator

#define T_TOK 16384
#define DIM   768
#define NE    8
#define HH    3072
#define CH    1536      // H chunk
#define NCH   2
#define MCAP  33792     // max padded slot rows (32768 + 8*127, rounded to 128)

// ---- workspace layout (bytes) ----
#define O_W1T 0u                         // E*HH*DIM*2 = 37,748,736  (bf16, [E][H][D])
#define O_W2T 37748736u                  // 37,748,736               (bf16, [E][D][H])
#define O_XBF 75497472u                  // T*D*2 = 25,165,824       (bf16, [T][D])
#define O_HBF 100663296u                 // MCAP*CH*2 = 103,809,024  (bf16, [MCAP][CH])
#define O_STK 204472320u                 // MCAP*4 slot_token
#define O_SGT 204607488u                 // MCAP*4 slot_gate
#define O_TE  204742656u                 // T*2*4 top-2 expert ids
#define O_TG  204873728u                 // T*2*4 top-2 gates
#define O_MET 205004800u                 // counts[8] fill[8] offs[9]
// total ~195.6 MiB

__device__ __forceinline__ u16 f2bf(float f){
  uint32_t u = __float_as_uint(f);
  uint32_t r = (u + 0x7fffu + ((u >> 16) & 1u)) >> 16;  // RNE
  return (u16)r;
}

// ================= casts / transposes =================
__global__ void k_transposeW1(const float* __restrict__ W1, u16* __restrict__ W1t){
  __shared__ float tile[32][33];
  int e = blockIdx.z;
  int h0 = blockIdx.x * 32, d0 = blockIdx.y * 32;
  const float* src = W1 + (size_t)e * DIM * HH;     // [D][H]
  u16* dst = W1t + (size_t)e * HH * DIM;            // [H][D]
  int tx = threadIdx.x, ty = threadIdx.y;
  #pragma unroll
  for (int j = 0; j < 4; j++)
    tile[ty + 8*j][tx] = src[(size_t)(d0 + ty + 8*j) * HH + h0 + tx];
  __syncthreads();
  #pragma unroll
  for (int j = 0; j < 4; j++)
    dst[(size_t)(h0 + ty + 8*j) * DIM + d0 + tx] = f2bf(tile[tx][ty + 8*j]);
}

__global__ void k_transposeW2(const float* __restrict__ W2, u16* __restrict__ W2t){
  __shared__ float tile[32][33];
  int e = blockIdx.z;
  int d0 = blockIdx.x * 32, h0 = blockIdx.y * 32;
  const float* src = W2 + (size_t)e * HH * DIM;     // [H][D]
  u16* dst = W2t + (size_t)e * DIM * HH;            // [D][H]
  int tx = threadIdx.x, ty = threadIdx.y;
  #pragma unroll
  for (int j = 0; j < 4; j++)
    tile[ty + 8*j][tx] = src[(size_t)(h0 + ty + 8*j) * DIM + d0 + tx];
  __syncthreads();
  #pragma unroll
  for (int j = 0; j < 4; j++)
    dst[(size_t)(d0 + ty + 8*j) * HH + h0 + tx] = f2bf(tile[tx][ty + 8*j]);
}

__global__ void k_castX(const float* __restrict__ x, u16* __restrict__ Xbf){
  int i = blockIdx.x * blockDim.x + threadIdx.x;
  const int n4 = T_TOK * DIM / 4;
  for (int idx = i; idx < n4; idx += gridDim.x * blockDim.x){
    float4 v = ((const float4*)x)[idx];
    ushort4 o;
    o.x = f2bf(v.x); o.y = f2bf(v.y); o.z = f2bf(v.z); o.w = f2bf(v.w);
    ((ushort4*)Xbf)[idx] = o;
  }
}

// ================= router =================
__global__ void k_router(const float* __restrict__ x, const float* __restrict__ Wg,
                         const float* __restrict__ bg,
                         int* __restrict__ tE, float* __restrict__ tG, int* __restrict__ counts){
  int t = blockIdx.x;
  int l = threadIdx.x;                 // 64 lanes, one wave
  const float* xr = x + (size_t)t * DIM;
  float acc[NE];
  #pragma unroll
  for (int e = 0; e < NE; e++) acc[e] = 0.f;
  #pragma unroll
  for (int j = 0; j < DIM / 64; j++){
    int c = l + 64 * j;
    float xv = xr[c];
    const float4* wr4 = (const float4*)(Wg + (size_t)c * NE);
    float4 w0 = wr4[0], w1 = wr4[1];
    acc[0] += xv * w0.x; acc[1] += xv * w0.y; acc[2] += xv * w0.z; acc[3] += xv * w0.w;
    acc[4] += xv * w1.x; acc[5] += xv * w1.y; acc[6] += xv * w1.z; acc[7] += xv * w1.w;
  }
  #pragma unroll
  for (int off = 32; off; off >>= 1)
    #pragma unroll
    for (int e = 0; e < NE; e++) acc[e] += __shfl_xor(acc[e], off, 64);

  float lgt[NE];
  #pragma unroll
  for (int e = 0; e < NE; e++) lgt[e] = acc[e] + bg[e];

  int i0 = 0; float v0 = lgt[0];
  #pragma unroll
  for (int e = 1; e < NE; e++) if (lgt[e] > v0){ v0 = lgt[e]; i0 = e; }
  int i1 = -1; float v1 = -1e30f;
  #pragma unroll
  for (int e = 0; e < NE; e++) if (e != i0 && lgt[e] > v1){ v1 = lgt[e]; i1 = e; }

  float ed = expf(v1 - v0);            // <= 1
  float g1 = ed / (1.f + ed);
  float g0 = 1.f / (1.f + ed);

  if (l == 0){
    tE[2*t] = i0; tE[2*t+1] = i1;
    tG[2*t] = g0; tG[2*t+1] = g1;
    atomicAdd(&counts[i0], 1);
    atomicAdd(&counts[i1], 1);
  }
}

__global__ void k_scan(const int* __restrict__ counts, int* __restrict__ offs){
  if (threadIdx.x == 0){
    int o = 0;
    for (int e = 0; e < NE; e++){ offs[e] = o; o += (counts[e] + 127) & ~127; }
    offs[NE] = o;
  }
}

__global__ void k_scatter(const int* __restrict__ tE, const float* __restrict__ tG,
                          const int* __restrict__ offs, int* __restrict__ fill,
                          int* __restrict__ slot_token, float* __restrict__ slot_gate){
  int t = blockIdx.x * blockDim.x + threadIdx.x;
  if (t >= T_TOK) return;
  #pragma unroll
  for (int k = 0; k < 2; k++){
    int e = tE[2*t + k];
    int pos = offs[e] + atomicAdd(&fill[e], 1);
    slot_token[pos] = t;
    slot_gate[pos]  = tG[2*t + k];
  }
}

// out init = g0*b2[e0] + g1*b2[e1]  (also serves as the zero-init of d_out)
__global__ void k_outinit(const int* __restrict__ tE, const float* __restrict__ tG,
                          const float* __restrict__ b2, float* __restrict__ out){
  int t = blockIdx.x;
  int e0 = tE[2*t], e1 = tE[2*t+1];
  float g0 = tG[2*t], g1 = tG[2*t+1];
  const float* r0 = b2 + (size_t)e0 * DIM;
  const float* r1 = b2 + (size_t)e1 * DIM;
  float* o = out + (size_t)t * DIM;
  #pragma unroll
  for (int j = 0; j < DIM / 256; j++){
    int c = threadIdx.x + 256 * j;
    o[c] = g0 * r0[c] + g1 * r1[c];
  }
}

// ================= grouped GEMMs (128x128 tile, 4 waves, 4x4 frags, 16x16x32 bf16) =================
// GEMM1: H[slot][h] = relu(X[token] @ W1[e] + b1[e]) * gate   (K = DIM = 768)
__global__ __launch_bounds__(256) void k_gemm1(
    const u16* __restrict__ Xbf, const u16* __restrict__ W1t, const float* __restrict__ b1,
    const int* __restrict__ slot_token, const float* __restrict__ slot_gate,
    const int* __restrict__ offs, u16* __restrict__ Hbuf, int cbase)
{
  int e = blockIdx.z, mt = blockIdx.y, nt = blockIdx.x;
  int mbase = offs[e];
  int pc = offs[e+1] - mbase;
  if (mt * 128 >= pc) return;
  int grb = mbase + mt * 128;
  int nb = nt * 128;              // col base within chunk
  int habs = cbase + nb;          // absolute h col base

  __shared__ u16 As[128 * 40];    // [128][32+8] bf16, +16B pad -> conflict-free b128
  __shared__ u16 Bs[128 * 40];

  int tid = threadIdx.x;
  int sr = tid >> 1, sc = tid & 1;
  int tokA = slot_token[grb + sr];
  const u16* Aptr = Xbf + (size_t)tokA * DIM + sc * 16;
  const u16* Bptr = W1t + ((size_t)e * HH + habs + sr) * DIM + sc * 16;
  u16* AsW = &As[sr * 40 + sc * 16];
  u16* BsW = &Bs[sr * 40 + sc * 16];

  int4 ra0 = *(const int4*)(Aptr);
  int4 ra1 = *(const int4*)(Aptr + 8);
  int4 rb0 = *(const int4*)(Bptr);
  int4 rb1 = *(const int4*)(Bptr + 8);

  int w = tid >> 6, lane = tid & 63, lm = lane & 15, lg = lane >> 4;
  int wr = (w >> 1) * 64, wc = (w & 1) * 64;

  v4f acc[4][4];
  #pragma unroll
  for (int mi = 0; mi < 4; mi++)
    #pragma unroll
    for (int ni = 0; ni < 4; ni++) acc[mi][ni] = 0.f;

  const int nk = DIM / 32;  // 24
  for (int kb = 0; kb < nk; ++kb){
    __syncthreads();
    *(int4*)(AsW) = ra0; *(int4*)(AsW + 8) = ra1;
    *(int4*)(BsW) = rb0; *(int4*)(BsW + 8) = rb1;
    __syncthreads();
    if (kb + 1 < nk){
      int o = (kb + 1) * 32;
      ra0 = *(const int4*)(Aptr + o); ra1 = *(const int4*)(Aptr + o + 8);
      rb0 = *(const int4*)(Bptr + o); rb1 = *(const int4*)(Bptr + o + 8);
    }
    v8s af[4], bb[4];
    #pragma unroll
    for (int mi = 0; mi < 4; mi++) af[mi] = *(const v8s*)&As[(wr + mi*16 + lm) * 40 + lg * 8];
    #pragma unroll
    for (int ni = 0; ni < 4; ni++) bb[ni] = *(const v8s*)&Bs[(wc + ni*16 + lm) * 40 + lg * 8];
    #pragma unroll
    for (int mi = 0; mi < 4; mi++)
      #pragma unroll
      for (int ni = 0; ni < 4; ni++)
        acc[mi][ni] = __builtin_amdgcn_mfma_f32_16x16x32_bf16(af[mi], bb[ni], acc[mi][ni], 0, 0, 0);
  }

  float b1v[4];
  #pragma unroll
  for (int ni = 0; ni < 4; ni++) b1v[ni] = b1[(size_t)e * HH + habs + wc + ni*16 + lm];
  #pragma unroll
  for (int mi = 0; mi < 4; mi++){
    int rbase = grb + wr + mi*16 + lg*4;
    float g[4];
    #pragma unroll
    for (int i = 0; i < 4; i++) g[i] = slot_gate[rbase + i];
    #pragma unroll
    for (int ni = 0; ni < 4; ni++){
      int col = nb + wc + ni*16 + lm;
      #pragma unroll
      for (int i = 0; i < 4; i++){
        float v = acc[mi][ni][i] + b1v[ni];
        v = fmaxf(v, 0.f) * g[i];
        Hbuf[(size_t)(rbase + i) * CH + col] = f2bf(v);
      }
    }
  }
}

// GEMM2: out[token][d] += H[slot] @ W2[e][chunk]   (K = CH = 1536)
__global__ __launch_bounds__(256) void k_gemm2(
    const u16* __restrict__ Hbuf, const u16* __restrict__ W2t,
    const int* __restrict__ slot_token, const int* __restrict__ offs,
    float* __restrict__ out, int cbase)
{
  int e = blockIdx.z, mt = blockIdx.y, nt = blockIdx.x;
  int mbase = offs[e];
  int pc = offs[e+1] - mbase;
  if (mt * 128 >= pc) return;
  int grb = mbase + mt * 128;
  int nb = nt * 128;              // d col base

  __shared__ u16 As[128 * 40];
  __shared__ u16 Bs[128 * 40];

  int tid = threadIdx.x;
  int sr = tid >> 1, sc = tid & 1;
  const u16* Aptr = Hbuf + (size_t)(grb + sr) * CH + sc * 16;
  const u16* Bptr = W2t + ((size_t)e * DIM + nb + sr) * HH + cbase + sc * 16;
  u16* AsW = &As[sr * 40 + sc * 16];
  u16* BsW = &Bs[sr * 40 + sc * 16];

  int4 ra0 = *(const int4*)(Aptr);
  int4 ra1 = *(const int4*)(Aptr + 8);
  int4 rb0 = *(const int4*)(Bptr);
  int4 rb1 = *(const int4*)(Bptr + 8);

  int w = tid >> 6, lane = tid & 63, lm = lane & 15, lg = lane >> 4;
  int wr = (w >> 1) * 64, wc = (w & 1) * 64;

  v4f acc[4][4];
  #pragma unroll
  for (int mi = 0; mi < 4; mi++)
    #pragma unroll
    for (int ni = 0; ni < 4; ni++) acc[mi][ni] = 0.f;

  const int nk = CH / 32;  // 48
  for (int kb = 0; kb < nk; ++kb){
    __syncthreads();
    *(int4*)(AsW) = ra0; *(int4*)(AsW + 8) = ra1;
    *(int4*)(BsW) = rb0; *(int4*)(BsW + 8) = rb1;
    __syncthreads();
    if (kb + 1 < nk){
      int o = (kb + 1) * 32;
      ra0 = *(const int4*)(Aptr + o); ra1 = *(const int4*)(Aptr + o + 8);
      rb0 = *(const int4*)(Bptr + o); rb1 = *(const int4*)(Bptr + o + 8);
    }
    v8s af[4], bb[4];
    #pragma unroll
    for (int mi = 0; mi < 4; mi++) af[mi] = *(const v8s*)&As[(wr + mi*16 + lm) * 40 + lg * 8];
    #pragma unroll
    for (int ni = 0; ni < 4; ni++) bb[ni] = *(const v8s*)&Bs[(wc + ni*16 + lm) * 40 + lg * 8];
    #pragma unroll
    for (int mi = 0; mi < 4; mi++)
      #pragma unroll
      for (int ni = 0; ni < 4; ni++)
        acc[mi][ni] = __builtin_amdgcn_mfma_f32_16x16x32_bf16(af[mi], bb[ni], acc[mi][ni], 0, 0, 0);
  }

  #pragma unroll
  for (int mi = 0; mi < 4; mi++){
    int rbase = grb + wr + mi*16 + lg*4;
    int tok[4];
    #pragma unroll
    for (int i = 0; i < 4; i++) tok[i] = slot_token[rbase + i];
    #pragma unroll
    for (int ni = 0; ni < 4; ni++){
      int col = nb + wc + ni*16 + lm;
      #pragma unroll
      for (int i = 0; i < 4; i++)
        unsafeAtomicAdd(&out[(size_t)tok[i] * DIM + col], acc[mi][ni][i]);
    }
  }
}

// ================= launch =================
extern "C" void kernel_launch(void* const* d_in, const int* in_sizes, int n_in,
                              void* d_out, int out_size, void* d_ws, size_t ws_size,
                              hipStream_t stream)
{
  const float* x  = (const float*)d_in[0];
  const float* Wg = (const float*)d_in[1];
  const float* bg = (const float*)d_in[2];
  const float* W1 = (const float*)d_in[3];
  const float* b1 = (const float*)d_in[4];
  const float* W2 = (const float*)d_in[5];
  const float* b2 = (const float*)d_in[6];
  float* out = (float*)d_out;
  char* ws = (char*)d_ws;

  u16*   W1t        = (u16*)(ws + O_W1T);
  u16*   W2t        = (u16*)(ws + O_W2T);
  u16*   Xbf        = (u16*)(ws + O_XBF);
  u16*   Hbuf       = (u16*)(ws + O_HBF);
  int*   slot_token = (int*)(ws + O_STK);
  float* slot_gate  = (float*)(ws + O_SGT);
  int*   tE         = (int*)(ws + O_TE);
  float* tG         = (float*)(ws + O_TG);
  int*   meta       = (int*)(ws + O_MET);
  int*   counts = meta;
  int*   fill   = meta + 8;
  int*   offs   = meta + 16;

  // zero slot arrays (pad rows => token 0, gate 0) and counts/fill
  hipMemsetAsync(ws + O_STK, 0, 2 * MCAP * 4, stream);
  hipMemsetAsync(ws + O_MET, 0, 64, stream);

  k_transposeW1<<<dim3(HH/32, DIM/32, NE), dim3(32, 8), 0, stream>>>(W1, W1t);
  k_transposeW2<<<dim3(DIM/32, HH/32, NE), dim3(32, 8), 0, stream>>>(W2, W2t);
  k_castX<<<3072, 256, 0, stream>>>(x, Xbf);

  k_router<<<T_TOK, 64, 0, stream>>>(x, Wg, bg, tE, tG, counts);
  k_scan<<<1, 1, 0, stream>>>(counts, offs);
  k_scatter<<<T_TOK/256, 256, 0, stream>>>(tE, tG, offs, fill, slot_token, slot_gate);
  k_outinit<<<T_TOK, 256, 0, stream>>>(tE, tG, b2, out);

  for (int c = 0; c < NCH; c++){
    k_gemm1<<<dim3(CH/128, 128, NE), 256, 0, stream>>>(Xbf, W1t, b1, slot_token, slot_gate, offs, Hbuf, c * CH);
    k_gemm2<<<dim3(DIM/128, 128, NE), 256, 0, stream>>>(Hbuf, W2t, slot_token, offs, out, c * CH);
  }
}

// Round 2
// 786.781 us; speedup vs baseline: 1.6410x; 1.6410x over previous
//
#include <hip/hip_runtime.h>
#include <stdint.h>

typedef unsigned short u16;
typedef __attribute__((ext_vector_type(8))) short v8s;   // 8 x bf16 (as raw shorts)
typedef __attribute__((ext_vector_type(4))) float v4f;   // MFMA accumulator

#define T_TOK 16384
#define DIM   768
#define NE    8
#define HH    3072
#define CH    1536      // H chunk
#define NCH   2
#define MCAP  33792     // max padded slot rows (32768 + 8*127, rounded to 128)

// ---- workspace layout (bytes) ----
#define O_W1T 0u                         // E*HH*DIM*2 = 37,748,736  (bf16, [E][H][D])
#define O_W2T 37748736u                  // 37,748,736               (bf16, [E][D][H])
#define O_XBF 75497472u                  // T*D*2 = 25,165,824       (bf16, [T][D])
#define O_HBF 100663296u                 // MCAP*CH*2 = 103,809,024  (bf16, [MCAP][CH])
#define O_STK 204472320u                 // MCAP*4 slot_token
#define O_SGT 204607488u                 // MCAP*4 slot_gate
#define O_TE  204742656u                 // T*2*4 top-2 expert ids
#define O_TG  204873728u                 // T*2*4 top-2 gates
#define O_MET 205004800u                 // counts[8] fill[8] offs[9]
// total ~195.6 MiB

__device__ __forceinline__ u16 f2bf(float f){
  uint32_t u = __float_as_uint(f);
  uint32_t r = (u + 0x7fffu + ((u >> 16) & 1u)) >> 16;  // RNE
  return (u16)r;
}

// ================= casts / transposes =================
__global__ void k_transposeW1(const float* __restrict__ W1, u16* __restrict__ W1t){
  __shared__ float tile[32][33];
  int e = blockIdx.z;
  int h0 = blockIdx.x * 32, d0 = blockIdx.y * 32;
  const float* src = W1 + (size_t)e * DIM * HH;     // [D][H]
  u16* dst = W1t + (size_t)e * HH * DIM;            // [H][D]
  int tx = threadIdx.x, ty = threadIdx.y;
  #pragma unroll
  for (int j = 0; j < 4; j++)
    tile[ty + 8*j][tx] = src[(size_t)(d0 + ty + 8*j) * HH + h0 + tx];
  __syncthreads();
  #pragma unroll
  for (int j = 0; j < 4; j++)
    dst[(size_t)(h0 + ty + 8*j) * DIM + d0 + tx] = f2bf(tile[tx][ty + 8*j]);
}

__global__ void k_transposeW2(const float* __restrict__ W2, u16* __restrict__ W2t){
  __shared__ float tile[32][33];
  int e = blockIdx.z;
  int d0 = blockIdx.x * 32, h0 = blockIdx.y * 32;
  const float* src = W2 + (size_t)e * HH * DIM;     // [H][D]
  u16* dst = W2t + (size_t)e * DIM * HH;            // [D][H]
  int tx = threadIdx.x, ty = threadIdx.y;
  #pragma unroll
  for (int j = 0; j < 4; j++)
    tile[ty + 8*j][tx] = src[(size_t)(h0 + ty + 8*j) * DIM + d0 + tx];
  __syncthreads();
  #pragma unroll
  for (int j = 0; j < 4; j++)
    dst[(size_t)(d0 + ty + 8*j) * HH + h0 + tx] = f2bf(tile[tx][ty + 8*j]);
}

__global__ void k_castX(const float* __restrict__ x, u16* __restrict__ Xbf){
  int i = blockIdx.x * blockDim.x + threadIdx.x;
  const int n4 = T_TOK * DIM / 4;
  for (int idx = i; idx < n4; idx += gridDim.x * blockDim.x){
    float4 v = ((const float4*)x)[idx];
    ushort4 o;
    o.x = f2bf(v.x); o.y = f2bf(v.y); o.z = f2bf(v.z); o.w = f2bf(v.w);
    ((ushort4*)Xbf)[idx] = o;
  }
}

// ================= router (no atomics) =================
__global__ __launch_bounds__(256) void k_router(
    const float* __restrict__ x, const float* __restrict__ Wg, const float* __restrict__ bg,
    int* __restrict__ tE, float* __restrict__ tG){
  int t = blockIdx.x * 4 + (threadIdx.x >> 6);
  int l = threadIdx.x & 63;
  const float* xr = x + (size_t)t * DIM;
  float acc[NE];
  #pragma unroll
  for (int e = 0; e < NE; e++) acc[e] = 0.f;
  #pragma unroll
  for (int j = 0; j < DIM / 64; j++){
    int c = l + 64 * j;
    float xv = xr[c];
    const float4* wr4 = (const float4*)(Wg + (size_t)c * NE);
    float4 w0 = wr4[0], w1 = wr4[1];
    acc[0] += xv * w0.x; acc[1] += xv * w0.y; acc[2] += xv * w0.z; acc[3] += xv * w0.w;
    acc[4] += xv * w1.x; acc[5] += xv * w1.y; acc[6] += xv * w1.z; acc[7] += xv * w1.w;
  }
  #pragma unroll
  for (int off = 32; off; off >>= 1)
    #pragma unroll
    for (int e = 0; e < NE; e++) acc[e] += __shfl_xor(acc[e], off, 64);

  if (l == 0){
    float lgt[NE];
    #pragma unroll
    for (int e = 0; e < NE; e++) lgt[e] = acc[e] + bg[e];

    int i0 = 0; float v0 = lgt[0];
    #pragma unroll
    for (int e = 1; e < NE; e++) if (lgt[e] > v0){ v0 = lgt[e]; i0 = e; }
    int i1 = -1; float v1 = -1e30f;
    #pragma unroll
    for (int e = 0; e < NE; e++) if (e != i0 && lgt[e] > v1){ v1 = lgt[e]; i1 = e; }

    float ed = expf(v1 - v0);            // <= 1
    float g1 = ed / (1.f + ed);
    float g0 = 1.f / (1.f + ed);

    tE[2*t] = i0; tE[2*t+1] = i1;
    tG[2*t] = g0; tG[2*t+1] = g1;
  }
}

// ================= count (register histogram, 1024 atomics total) =================
__global__ __launch_bounds__(256) void k_count(const int* __restrict__ tE, int* __restrict__ counts){
  int i = blockIdx.x * blockDim.x + threadIdx.x;   // 32 blocks x 256 = 8192 threads
  int c[NE];
  #pragma unroll
  for (int e = 0; e < NE; e++) c[e] = 0;
  for (int j = i; j < 2 * T_TOK; j += 32 * 256){
    int v = tE[j];
    #pragma unroll
    for (int e = 0; e < NE; e++) c[e] += (v == e);
  }
  #pragma unroll
  for (int off = 32; off; off >>= 1)
    #pragma unroll
    for (int e = 0; e < NE; e++) c[e] += __shfl_xor(c[e], off, 64);
  if ((threadIdx.x & 63) == 0){
    #pragma unroll
    for (int e = 0; e < NE; e++) atomicAdd(&counts[e], c[e]);
  }
}

__global__ void k_scan(const int* __restrict__ counts, int* __restrict__ offs){
  if (threadIdx.x == 0){
    int o = 0;
    for (int e = 0; e < NE; e++){ offs[e] = o; o += (counts[e] + 127) & ~127; }
    offs[NE] = o;
  }
}

// ================= scatter (ballot-rank + per-block reservation, 8 atomics/block) =================
__global__ __launch_bounds__(256) void k_scatter(
    const int* __restrict__ tE, const float* __restrict__ tG,
    const int* __restrict__ offs, int* __restrict__ fill,
    int* __restrict__ slot_token, float* __restrict__ slot_gate){
  int t = blockIdx.x * 256 + threadIdx.x;
  int lane = threadIdx.x & 63, w = threadIdx.x >> 6;
  int e0 = tE[2*t], e1 = tE[2*t+1];
  float g0 = tG[2*t], g1 = tG[2*t+1];

  __shared__ int wcnt[4][NE];
  __shared__ int woff[4][NE];
  __shared__ int bbase[NE];

  uint64_t below = (1ull << lane) - 1ull;
  int rank0 = 0, rank1 = 0;
  #pragma unroll
  for (int e = 0; e < NE; e++){
    uint64_t m0 = __ballot(e0 == e);
    uint64_t m1 = __ballot(e1 == e);
    int c0 = __popcll(m0);
    if (e0 == e) rank0 = __popcll(m0 & below);
    if (e1 == e) rank1 = c0 + __popcll(m1 & below);
    if (lane == 0) wcnt[w][e] = c0 + __popcll(m1);
  }
  __syncthreads();
  if (threadIdx.x < NE){
    int e = threadIdx.x;
    int s = 0;
    #pragma unroll
    for (int ww = 0; ww < 4; ww++){ woff[ww][e] = s; s += wcnt[ww][e]; }
    bbase[e] = atomicAdd(&fill[e], s);
  }
  __syncthreads();
  int p0 = offs[e0] + bbase[e0] + woff[w][e0] + rank0;
  slot_token[p0] = t; slot_gate[p0] = g0;
  int p1 = offs[e1] + bbase[e1] + woff[w][e1] + rank1;
  slot_token[p1] = t; slot_gate[p1] = g1;
}

// out init = g0*b2[e0] + g1*b2[e1]  (also serves as the zero-init of d_out)
__global__ void k_outinit(const int* __restrict__ tE, const float* __restrict__ tG,
                          const float* __restrict__ b2, float* __restrict__ out){
  int t = blockIdx.x;
  int e0 = tE[2*t], e1 = tE[2*t+1];
  float g0 = tG[2*t], g1 = tG[2*t+1];
  const float* r0 = b2 + (size_t)e0 * DIM;
  const float* r1 = b2 + (size_t)e1 * DIM;
  float* o = out + (size_t)t * DIM;
  #pragma unroll
  for (int j = 0; j < DIM / 256; j++){
    int c = threadIdx.x + 256 * j;
    o[c] = g0 * r0[c] + g1 * r1[c];
  }
}

// ================= grouped GEMMs (128x128 tile, 4 waves, 4x4 frags, 16x16x32 bf16) =================
// GEMM1: H[slot][h] = relu(X[token] @ W1[e] + b1[e]) * gate   (K = DIM = 768)
__global__ __launch_bounds__(256) void k_gemm1(
    const u16* __restrict__ Xbf, const u16* __restrict__ W1t, const float* __restrict__ b1,
    const int* __restrict__ slot_token, const float* __restrict__ slot_gate,
    const int* __restrict__ offs, u16* __restrict__ Hbuf, int cbase)
{
  int e = blockIdx.z, mt = blockIdx.y, nt = blockIdx.x;
  int mbase = offs[e];
  int pc = offs[e+1] - mbase;
  if (mt * 128 >= pc) return;
  int grb = mbase + mt * 128;
  int nb = nt * 128;              // col base within chunk
  int habs = cbase + nb;          // absolute h col base

  __shared__ u16 As[128 * 40];    // [128][32+8] bf16, +16B pad -> conflict-free b128
  __shared__ u16 Bs[128 * 40];

  int tid = threadIdx.x;
  int sr = tid >> 1, sc = tid & 1;
  int tokA = slot_token[grb + sr];
  const u16* Aptr = Xbf + (size_t)tokA * DIM + sc * 16;
  const u16* Bptr = W1t + ((size_t)e * HH + habs + sr) * DIM + sc * 16;
  u16* AsW = &As[sr * 40 + sc * 16];
  u16* BsW = &Bs[sr * 40 + sc * 16];

  int4 ra0 = *(const int4*)(Aptr);
  int4 ra1 = *(const int4*)(Aptr + 8);
  int4 rb0 = *(const int4*)(Bptr);
  int4 rb1 = *(const int4*)(Bptr + 8);

  int w = tid >> 6, lane = tid & 63, lm = lane & 15, lg = lane >> 4;
  int wr = (w >> 1) * 64, wc = (w & 1) * 64;

  v4f acc[4][4];
  #pragma unroll
  for (int mi = 0; mi < 4; mi++)
    #pragma unroll
    for (int ni = 0; ni < 4; ni++) acc[mi][ni] = 0.f;

  const int nk = DIM / 32;  // 24
  for (int kb = 0; kb < nk; ++kb){
    __syncthreads();
    *(int4*)(AsW) = ra0; *(int4*)(AsW + 8) = ra1;
    *(int4*)(BsW) = rb0; *(int4*)(BsW + 8) = rb1;
    __syncthreads();
    if (kb + 1 < nk){
      int o = (kb + 1) * 32;
      ra0 = *(const int4*)(Aptr + o); ra1 = *(const int4*)(Aptr + o + 8);
      rb0 = *(const int4*)(Bptr + o); rb1 = *(const int4*)(Bptr + o + 8);
    }
    v8s af[4], bb[4];
    #pragma unroll
    for (int mi = 0; mi < 4; mi++) af[mi] = *(const v8s*)&As[(wr + mi*16 + lm) * 40 + lg * 8];
    #pragma unroll
    for (int ni = 0; ni < 4; ni++) bb[ni] = *(const v8s*)&Bs[(wc + ni*16 + lm) * 40 + lg * 8];
    #pragma unroll
    for (int mi = 0; mi < 4; mi++)
      #pragma unroll
      for (int ni = 0; ni < 4; ni++)
        acc[mi][ni] = __builtin_amdgcn_mfma_f32_16x16x32_bf16(af[mi], bb[ni], acc[mi][ni], 0, 0, 0);
  }

  float b1v[4];
  #pragma unroll
  for (int ni = 0; ni < 4; ni++) b1v[ni] = b1[(size_t)e * HH + habs + wc + ni*16 + lm];
  #pragma unroll
  for (int mi = 0; mi < 4; mi++){
    int rbase = grb + wr + mi*16 + lg*4;
    float g[4];
    #pragma unroll
    for (int i = 0; i < 4; i++) g[i] = slot_gate[rbase + i];
    #pragma unroll
    for (int ni = 0; ni < 4; ni++){
      int col = nb + wc + ni*16 + lm;
      #pragma unroll
      for (int i = 0; i < 4; i++){
        float v = acc[mi][ni][i] + b1v[ni];
        v = fmaxf(v, 0.f) * g[i];
        Hbuf[(size_t)(rbase + i) * CH + col] = f2bf(v);
      }
    }
  }
}

// GEMM2: out[token][d] += H[slot] @ W2[e][chunk]   (K = CH = 1536)
__global__ __launch_bounds__(256) void k_gemm2(
    const u16* __restrict__ Hbuf, const u16* __restrict__ W2t,
    const int* __restrict__ slot_token, const int* __restrict__ offs,
    float* __restrict__ out, int cbase)
{
  int e = blockIdx.z, mt = blockIdx.y, nt = blockIdx.x;
  int mbase = offs[e];
  int pc = offs[e+1] - mbase;
  if (mt * 128 >= pc) return;
  int grb = mbase + mt * 128;
  int nb = nt * 128;              // d col base

  __shared__ u16 As[128 * 40];
  __shared__ u16 Bs[128 * 40];

  int tid = threadIdx.x;
  int sr = tid >> 1, sc = tid & 1;
  const u16* Aptr = Hbuf + (size_t)(grb + sr) * CH + sc * 16;
  const u16* Bptr = W2t + ((size_t)e * DIM + nb + sr) * HH + cbase + sc * 16;
  u16* AsW = &As[sr * 40 + sc * 16];
  u16* BsW = &Bs[sr * 40 + sc * 16];

  int4 ra0 = *(const int4*)(Aptr);
  int4 ra1 = *(const int4*)(Aptr + 8);
  int4 rb0 = *(const int4*)(Bptr);
  int4 rb1 = *(const int4*)(Bptr + 8);

  int w = tid >> 6, lane = tid & 63, lm = lane & 15, lg = lane >> 4;
  int wr = (w >> 1) * 64, wc = (w & 1) * 64;

  v4f acc[4][4];
  #pragma unroll
  for (int mi = 0; mi < 4; mi++)
    #pragma unroll
    for (int ni = 0; ni < 4; ni++) acc[mi][ni] = 0.f;

  const int nk = CH / 32;  // 48
  for (int kb = 0; kb < nk; ++kb){
    __syncthreads();
    *(int4*)(AsW) = ra0; *(int4*)(AsW + 8) = ra1;
    *(int4*)(BsW) = rb0; *(int4*)(BsW + 8) = rb1;
    __syncthreads();
    if (kb + 1 < nk){
      int o = (kb + 1) * 32;
      ra0 = *(const int4*)(Aptr + o); ra1 = *(const int4*)(Aptr + o + 8);
      rb0 = *(const int4*)(Bptr + o); rb1 = *(const int4*)(Bptr + o + 8);
    }
    v8s af[4], bb[4];
    #pragma unroll
    for (int mi = 0; mi < 4; mi++) af[mi] = *(const v8s*)&As[(wr + mi*16 + lm) * 40 + lg * 8];
    #pragma unroll
    for (int ni = 0; ni < 4; ni++) bb[ni] = *(const v8s*)&Bs[(wc + ni*16 + lm) * 40 + lg * 8];
    #pragma unroll
    for (int mi = 0; mi < 4; mi++)
      #pragma unroll
      for (int ni = 0; ni < 4; ni++)
        acc[mi][ni] = __builtin_amdgcn_mfma_f32_16x16x32_bf16(af[mi], bb[ni], acc[mi][ni], 0, 0, 0);
  }

  #pragma unroll
  for (int mi = 0; mi < 4; mi++){
    int rbase = grb + wr + mi*16 + lg*4;
    int tok[4];
    #pragma unroll
    for (int i = 0; i < 4; i++) tok[i] = slot_token[rbase + i];
    #pragma unroll
    for (int ni = 0; ni < 4; ni++){
      int col = nb + wc + ni*16 + lm;
      #pragma unroll
      for (int i = 0; i < 4; i++)
        unsafeAtomicAdd(&out[(size_t)tok[i] * DIM + col], acc[mi][ni][i]);
    }
  }
}

// ================= launch =================
extern "C" void kernel_launch(void* const* d_in, const int* in_sizes, int n_in,
                              void* d_out, int out_size, void* d_ws, size_t ws_size,
                              hipStream_t stream)
{
  const float* x  = (const float*)d_in[0];
  const float* Wg = (const float*)d_in[1];
  const float* bg = (const float*)d_in[2];
  const float* W1 = (const float*)d_in[3];
  const float* b1 = (const float*)d_in[4];
  const float* W2 = (const float*)d_in[5];
  const float* b2 = (const float*)d_in[6];
  float* out = (float*)d_out;
  char* ws = (char*)d_ws;

  u16*   W1t        = (u16*)(ws + O_W1T);
  u16*   W2t        = (u16*)(ws + O_W2T);
  u16*   Xbf        = (u16*)(ws + O_XBF);
  u16*   Hbuf       = (u16*)(ws + O_HBF);
  int*   slot_token = (int*)(ws + O_STK);
  float* slot_gate  = (float*)(ws + O_SGT);
  int*   tE         = (int*)(ws + O_TE);
  float* tG         = (float*)(ws + O_TG);
  int*   meta       = (int*)(ws + O_MET);
  int*   counts = meta;
  int*   fill   = meta + 8;
  int*   offs   = meta + 16;

  // zero slot arrays (pad rows => token 0, gate 0) and counts/fill
  hipMemsetAsync(ws + O_STK, 0, 2 * MCAP * 4, stream);
  hipMemsetAsync(ws + O_MET, 0, 64, stream);

  k_transposeW1<<<dim3(HH/32, DIM/32, NE), dim3(32, 8), 0, stream>>>(W1, W1t);
  k_transposeW2<<<dim3(DIM/32, HH/32, NE), dim3(32, 8), 0, stream>>>(W2, W2t);
  k_castX<<<3072, 256, 0, stream>>>(x, Xbf);

  k_router<<<T_TOK/4, 256, 0, stream>>>(x, Wg, bg, tE, tG);
  k_count<<<32, 256, 0, stream>>>(tE, counts);
  k_scan<<<1, 1, 0, stream>>>(counts, offs);
  k_scatter<<<T_TOK/256, 256, 0, stream>>>(tE, tG, offs, fill, slot_token, slot_gate);
  k_outinit<<<T_TOK, 256, 0, stream>>>(tE, tG, b2, out);

  for (int c = 0; c < NCH; c++){
    k_gemm1<<<dim3(CH/128, 128, NE), 256, 0, stream>>>(Xbf, W1t, b1, slot_token, slot_gate, offs, Hbuf, c * CH);
    k_gemm2<<<dim3(DIM/128, 128, NE), 256, 0, stream>>>(Hbuf, W2t, slot_token, offs, out, c * CH);
  }
}

// Round 3
// 684.875 us; speedup vs baseline: 1.8851x; 1.1488x over previous
//
#include <hip/hip_runtime.h>
#include <stdint.h>

typedef unsigned short u16;
typedef __attribute__((ext_vector_type(8))) short v8s;   // 8 x bf16 (as raw shorts)
typedef __attribute__((ext_vector_type(4))) float v4f;   // MFMA accumulator

#define T_TOK 16384
#define DIM   768
#define NE    8
#define HH    3072
#define CH    1536      // H chunk
#define NCH   2
#define MCAP  33792     // max padded slot rows (32768 + 8*127, rounded to 128)

// ---- workspace layout (bytes) ----
#define O_W1T 0u            // 37,748,736  bf16 [E][H][D]
#define O_W2T 37748736u     // 37,748,736  bf16 [E][D][H]
#define O_XBF 75497472u     // 25,165,824  bf16 [T][D]
#define O_STK 100663296u    // MCAP*4 slot_token
#define O_SGT 100798464u    // MCAP*4 slot_gate
#define O_TE  100933632u    // T*2*4 expert ids
#define O_TG  101064704u    // T*2*4 gates
#define O_TS  101195776u    // T*2*4 token->slot
#define O_MET 101326848u    // counts/fill/offs
#define O_HBF 101327104u    // MCAP*CH*2 = 103,809,024
#define O_OBF 205136128u    // MCAP*DIM*2 = 51,904,512 (Tier A only)
#define WS_TIER_A 257040640ull

__device__ __forceinline__ u16 f2bf(float f){
  uint32_t u = __float_as_uint(f);
  uint32_t r = (u + 0x7fffu + ((u >> 16) & 1u)) >> 16;  // RNE
  return (u16)r;
}
__device__ __forceinline__ float bf2f(u16 v){
  return __uint_as_float(((uint32_t)v) << 16);
}
// async global->LDS, 16B per lane; LDS dest = wave-uniform base + lane*16
__device__ __forceinline__ void gll16(const u16* g, u16* l){
  __builtin_amdgcn_global_load_lds((const __attribute__((address_space(1))) uint32_t*)g,
                                   (__attribute__((address_space(3))) uint32_t*)l, 16, 0, 0);
}

// ================= casts / transposes =================
__global__ void k_transposeW1(const float* __restrict__ W1, u16* __restrict__ W1t){
  __shared__ float tile[32][33];
  int e = blockIdx.z;
  int h0 = blockIdx.x * 32, d0 = blockIdx.y * 32;
  const float* src = W1 + (size_t)e * DIM * HH;     // [D][H]
  u16* dst = W1t + (size_t)e * HH * DIM;            // [H][D]
  int tx = threadIdx.x, ty = threadIdx.y;
  #pragma unroll
  for (int j = 0; j < 4; j++)
    tile[ty + 8*j][tx] = src[(size_t)(d0 + ty + 8*j) * HH + h0 + tx];
  __syncthreads();
  #pragma unroll
  for (int j = 0; j < 4; j++)
    dst[(size_t)(h0 + ty + 8*j) * DIM + d0 + tx] = f2bf(tile[tx][ty + 8*j]);
}

__global__ void k_transposeW2(const float* __restrict__ W2, u16* __restrict__ W2t){
  __shared__ float tile[32][33];
  int e = blockIdx.z;
  int d0 = blockIdx.x * 32, h0 = blockIdx.y * 32;
  const float* src = W2 + (size_t)e * HH * DIM;     // [H][D]
  u16* dst = W2t + (size_t)e * DIM * HH;            // [D][H]
  int tx = threadIdx.x, ty = threadIdx.y;
  #pragma unroll
  for (int j = 0; j < 4; j++)
    tile[ty + 8*j][tx] = src[(size_t)(h0 + ty + 8*j) * DIM + d0 + tx];
  __syncthreads();
  #pragma unroll
  for (int j = 0; j < 4; j++)
    dst[(size_t)(d0 + ty + 8*j) * HH + h0 + tx] = f2bf(tile[tx][ty + 8*j]);
}

__global__ void k_castX(const float* __restrict__ x, u16* __restrict__ Xbf){
  int i = blockIdx.x * blockDim.x + threadIdx.x;
  const int n4 = T_TOK * DIM / 4;
  for (int idx = i; idx < n4; idx += gridDim.x * blockDim.x){
    float4 v = ((const float4*)x)[idx];
    ushort4 o;
    o.x = f2bf(v.x); o.y = f2bf(v.y); o.z = f2bf(v.z); o.w = f2bf(v.w);
    ((ushort4*)Xbf)[idx] = o;
  }
}

// ================= router (no atomics) =================
__global__ __launch_bounds__(256) void k_router(
    const float* __restrict__ x, const float* __restrict__ Wg, const float* __restrict__ bg,
    int* __restrict__ tE, float* __restrict__ tG){
  int t = blockIdx.x * 4 + (threadIdx.x >> 6);
  int l = threadIdx.x & 63;
  const float* xr = x + (size_t)t * DIM;
  float acc[NE];
  #pragma unroll
  for (int e = 0; e < NE; e++) acc[e] = 0.f;
  #pragma unroll
  for (int j = 0; j < DIM / 64; j++){
    int c = l + 64 * j;
    float xv = xr[c];
    const float4* wr4 = (const float4*)(Wg + (size_t)c * NE);
    float4 w0 = wr4[0], w1 = wr4[1];
    acc[0] += xv * w0.x; acc[1] += xv * w0.y; acc[2] += xv * w0.z; acc[3] += xv * w0.w;
    acc[4] += xv * w1.x; acc[5] += xv * w1.y; acc[6] += xv * w1.z; acc[7] += xv * w1.w;
  }
  #pragma unroll
  for (int off = 32; off; off >>= 1)
    #pragma unroll
    for (int e = 0; e < NE; e++) acc[e] += __shfl_xor(acc[e], off, 64);

  if (l == 0){
    float lgt[NE];
    #pragma unroll
    for (int e = 0; e < NE; e++) lgt[e] = acc[e] + bg[e];

    int i0 = 0; float v0 = lgt[0];
    #pragma unroll
    for (int e = 1; e < NE; e++) if (lgt[e] > v0){ v0 = lgt[e]; i0 = e; }
    int i1 = -1; float v1 = -1e30f;
    #pragma unroll
    for (int e = 0; e < NE; e++) if (e != i0 && lgt[e] > v1){ v1 = lgt[e]; i1 = e; }

    float ed = expf(v1 - v0);            // <= 1
    float g1 = ed / (1.f + ed);
    float g0 = 1.f / (1.f + ed);

    tE[2*t] = i0; tE[2*t+1] = i1;
    tG[2*t] = g0; tG[2*t+1] = g1;
  }
}

// ================= count (register histogram) =================
__global__ __launch_bounds__(256) void k_count(const int* __restrict__ tE, int* __restrict__ counts){
  int i = blockIdx.x * blockDim.x + threadIdx.x;   // 32 x 256
  int c[NE];
  #pragma unroll
  for (int e = 0; e < NE; e++) c[e] = 0;
  for (int j = i; j < 2 * T_TOK; j += 32 * 256){
    int v = tE[j];
    #pragma unroll
    for (int e = 0; e < NE; e++) c[e] += (v == e);
  }
  #pragma unroll
  for (int off = 32; off; off >>= 1)
    #pragma unroll
    for (int e = 0; e < NE; e++) c[e] += __shfl_xor(c[e], off, 64);
  if ((threadIdx.x & 63) == 0){
    #pragma unroll
    for (int e = 0; e < NE; e++) atomicAdd(&counts[e], c[e]);
  }
}

__global__ void k_scan(const int* __restrict__ counts, int* __restrict__ offs){
  if (threadIdx.x == 0){
    int o = 0;
    for (int e = 0; e < NE; e++){ offs[e] = o; o += (counts[e] + 127) & ~127; }
    offs[NE] = o;
  }
}

// ================= scatter (ballot-rank, 8 atomics/block) =================
__global__ __launch_bounds__(256) void k_scatter(
    const int* __restrict__ tE, const float* __restrict__ tG,
    const int* __restrict__ offs, int* __restrict__ fill,
    int* __restrict__ slot_token, float* __restrict__ slot_gate, int* __restrict__ tSlot){
  int t = blockIdx.x * 256 + threadIdx.x;
  int lane = threadIdx.x & 63, w = threadIdx.x >> 6;
  int e0 = tE[2*t], e1 = tE[2*t+1];
  float g0 = tG[2*t], g1 = tG[2*t+1];

  __shared__ int wcnt[4][NE];
  __shared__ int woff[4][NE];
  __shared__ int bbase[NE];

  uint64_t below = (1ull << lane) - 1ull;
  int rank0 = 0, rank1 = 0;
  #pragma unroll
  for (int e = 0; e < NE; e++){
    uint64_t m0 = __ballot(e0 == e);
    uint64_t m1 = __ballot(e1 == e);
    int c0 = __popcll(m0);
    if (e0 == e) rank0 = __popcll(m0 & below);
    if (e1 == e) rank1 = c0 + __popcll(m1 & below);
    if (lane == 0) wcnt[w][e] = c0 + __popcll(m1);
  }
  __syncthreads();
  if (threadIdx.x < NE){
    int e = threadIdx.x;
    int s = 0;
    #pragma unroll
    for (int ww = 0; ww < 4; ww++){ woff[ww][e] = s; s += wcnt[ww][e]; }
    bbase[e] = atomicAdd(&fill[e], s);
  }
  __syncthreads();
  int p0 = offs[e0] + bbase[e0] + woff[w][e0] + rank0;
  slot_token[p0] = t; slot_gate[p0] = g0; tSlot[2*t] = p0;
  int p1 = offs[e1] + bbase[e1] + woff[w][e1] + rank1;
  slot_token[p1] = t; slot_gate[p1] = g1; tSlot[2*t+1] = p1;
}

// Tier B only: out init = g0*b2[e0] + g1*b2[e1]
__global__ void k_outinit(const int* __restrict__ tE, const float* __restrict__ tG,
                          const float* __restrict__ b2, float* __restrict__ out){
  int t = blockIdx.x;
  int e0 = tE[2*t], e1 = tE[2*t+1];
  float g0 = tG[2*t], g1 = tG[2*t+1];
  const float* r0 = b2 + (size_t)e0 * DIM;
  const float* r1 = b2 + (size_t)e1 * DIM;
  float* o = out + (size_t)t * DIM;
  #pragma unroll
  for (int j = 0; j < DIM / 256; j++){
    int c = threadIdx.x + 256 * j;
    o[c] = g0 * r0[c] + g1 * r1[c];
  }
}

// ============ grouped GEMMs: m97 structure (global_load_lds, linear LDS, 128x128) ============
// GEMM1: H[slot][h] = relu(X[token] @ W1[e] + b1[e]) * gate   (K = DIM = 768)
__global__ __launch_bounds__(256) void k_gemm1(
    const u16* __restrict__ Xbf, const u16* __restrict__ W1t, const float* __restrict__ b1,
    const int* __restrict__ slot_token, const float* __restrict__ slot_gate,
    const int* __restrict__ offs, u16* __restrict__ Hbuf, int cbase)
{
  int e = blockIdx.z, mt = blockIdx.y, nt = blockIdx.x;
  int mbase = offs[e];
  int pc = offs[e+1] - mbase;
  if (mt * 128 >= pc) return;
  int grb = mbase + mt * 128;
  int nb = nt * 128;              // col base within chunk
  int habs = cbase + nb;          // absolute h col base

  __shared__ u16 As[128 * 32];    // linear: row stride 32 elems (64B) — required by global_load_lds
  __shared__ u16 Bs[128 * 32];

  int tid = threadIdx.x;
  int w = tid >> 6, lane = tid & 63;
  int lrow = lane >> 2, lu = lane & 3;          // 16 rows x 4 x 16B per wave-call
  int r0 = w * 32 + lrow, r1 = r0 + 16;

  const u16* ga0 = Xbf + (size_t)slot_token[grb + r0] * DIM + lu * 8;
  const u16* ga1 = Xbf + (size_t)slot_token[grb + r1] * DIM + lu * 8;
  const u16* gb0 = W1t + ((size_t)e * HH + habs + r0) * DIM + lu * 8;
  const u16* gb1 = W1t + ((size_t)e * HH + habs + r1) * DIM + lu * 8;
  u16* lA0 = &As[(w * 32) * 32];
  u16* lA1 = &As[(w * 32 + 16) * 32];
  u16* lB0 = &Bs[(w * 32) * 32];
  u16* lB1 = &Bs[(w * 32 + 16) * 32];

  int lm = lane & 15, lg = lane >> 4;
  int wr = (w >> 1) * 64, wc = (w & 1) * 64;
  const u16* rA[4]; const u16* rB[4];
  #pragma unroll
  for (int mi = 0; mi < 4; mi++) rA[mi] = &As[(wr + mi*16 + lm) * 32 + lg * 8];
  #pragma unroll
  for (int ni = 0; ni < 4; ni++) rB[ni] = &Bs[(wc + ni*16 + lm) * 32 + lg * 8];

  v4f acc[4][4];
  #pragma unroll
  for (int mi = 0; mi < 4; mi++)
    #pragma unroll
    for (int ni = 0; ni < 4; ni++) acc[mi][ni] = 0.f;

  const int nk = DIM / 32;  // 24
  for (int kb = 0; kb < nk; ++kb){
    __syncthreads();                       // prev reads done before DMA overwrite
    int o = kb * 32;
    gll16(ga0 + o, lA0); gll16(ga1 + o, lA1);
    gll16(gb0 + o, lB0); gll16(gb1 + o, lB1);
    __syncthreads();                       // compiler drains vmcnt(0) before barrier
    v8s af[4], bb[4];
    #pragma unroll
    for (int mi = 0; mi < 4; mi++) af[mi] = *(const v8s*)rA[mi];
    #pragma unroll
    for (int ni = 0; ni < 4; ni++) bb[ni] = *(const v8s*)rB[ni];
    #pragma unroll
    for (int mi = 0; mi < 4; mi++)
      #pragma unroll
      for (int ni = 0; ni < 4; ni++)
        acc[mi][ni] = __builtin_amdgcn_mfma_f32_16x16x32_bf16(af[mi], bb[ni], acc[mi][ni], 0, 0, 0);
  }

  float b1v[4];
  #pragma unroll
  for (int ni = 0; ni < 4; ni++) b1v[ni] = b1[(size_t)e * HH + habs + wc + ni*16 + lm];
  #pragma unroll
  for (int mi = 0; mi < 4; mi++){
    int rbase = grb + wr + mi*16 + lg*4;
    float g[4];
    #pragma unroll
    for (int i = 0; i < 4; i++) g[i] = slot_gate[rbase + i];
    #pragma unroll
    for (int ni = 0; ni < 4; ni++){
      int col = nb + wc + ni*16 + lm;
      #pragma unroll
      for (int i = 0; i < 4; i++){
        float v = acc[mi][ni][i] + b1v[ni];
        v = fmaxf(v, 0.f) * g[i];
        Hbuf[(size_t)(rbase + i) * CH + col] = f2bf(v);
      }
    }
  }
}

// GEMM2: Oslot[slot][d] (+)= H[slot] @ W2[e][chunk]    (K = CH)
// mode 0: atomic-add into out[token][d] (Tier B)
// mode 1: store to Obuf (first chunk, Tier A); mode 2: non-atomic RMW add (later chunks)
__global__ __launch_bounds__(256) void k_gemm2(
    const u16* __restrict__ Hbuf, const u16* __restrict__ W2t,
    const int* __restrict__ slot_token, const int* __restrict__ offs,
    float* __restrict__ out, u16* __restrict__ Obuf, int cbase, int mode)
{
  int e = blockIdx.z, mt = blockIdx.y, nt = blockIdx.x;
  int mbase = offs[e];
  int pc = offs[e+1] - mbase;
  if (mt * 128 >= pc) return;
  int grb = mbase + mt * 128;
  int nb = nt * 128;              // d col base

  __shared__ u16 As[128 * 32];
  __shared__ u16 Bs[128 * 32];

  int tid = threadIdx.x;
  int w = tid >> 6, lane = tid & 63;
  int lrow = lane >> 2, lu = lane & 3;
  int r0 = w * 32 + lrow, r1 = r0 + 16;

  const u16* ga0 = Hbuf + (size_t)(grb + r0) * CH + lu * 8;
  const u16* ga1 = Hbuf + (size_t)(grb + r1) * CH + lu * 8;
  const u16* gb0 = W2t + ((size_t)e * DIM + nb + r0) * HH + cbase + lu * 8;
  const u16* gb1 = W2t + ((size_t)e * DIM + nb + r1) * HH + cbase + lu * 8;
  u16* lA0 = &As[(w * 32) * 32];
  u16* lA1 = &As[(w * 32 + 16) * 32];
  u16* lB0 = &Bs[(w * 32) * 32];
  u16* lB1 = &Bs[(w * 32 + 16) * 32];

  int lm = lane & 15, lg = lane >> 4;
  int wr = (w >> 1) * 64, wc = (w & 1) * 64;
  const u16* rA[4]; const u16* rB[4];
  #pragma unroll
  for (int mi = 0; mi < 4; mi++) rA[mi] = &As[(wr + mi*16 + lm) * 32 + lg * 8];
  #pragma unroll
  for (int ni = 0; ni < 4; ni++) rB[ni] = &Bs[(wc + ni*16 + lm) * 32 + lg * 8];

  v4f acc[4][4];
  #pragma unroll
  for (int mi = 0; mi < 4; mi++)
    #pragma unroll
    for (int ni = 0; ni < 4; ni++) acc[mi][ni] = 0.f;

  const int nk = CH / 32;  // 48
  for (int kb = 0; kb < nk; ++kb){
    __syncthreads();
    int o = kb * 32;
    gll16(ga0 + o, lA0); gll16(ga1 + o, lA1);
    gll16(gb0 + o, lB0); gll16(gb1 + o, lB1);
    __syncthreads();
    v8s af[4], bb[4];
    #pragma unroll
    for (int mi = 0; mi < 4; mi++) af[mi] = *(const v8s*)rA[mi];
    #pragma unroll
    for (int ni = 0; ni < 4; ni++) bb[ni] = *(const v8s*)rB[ni];
    #pragma unroll
    for (int mi = 0; mi < 4; mi++)
      #pragma unroll
      for (int ni = 0; ni < 4; ni++)
        acc[mi][ni] = __builtin_amdgcn_mfma_f32_16x16x32_bf16(af[mi], bb[ni], acc[mi][ni], 0, 0, 0);
  }

  if (mode == 0){
    #pragma unroll
    for (int mi = 0; mi < 4; mi++){
      int rbase = grb + wr + mi*16 + lg*4;
      int tok[4];
      #pragma unroll
      for (int i = 0; i < 4; i++) tok[i] = slot_token[rbase + i];
      #pragma unroll
      for (int ni = 0; ni < 4; ni++){
        int col = nb + wc + ni*16 + lm;
        #pragma unroll
        for (int i = 0; i < 4; i++)
          unsafeAtomicAdd(&out[(size_t)tok[i] * DIM + col], acc[mi][ni][i]);
      }
    }
  } else if (mode == 1){
    #pragma unroll
    for (int mi = 0; mi < 4; mi++){
      int rbase = grb + wr + mi*16 + lg*4;
      #pragma unroll
      for (int ni = 0; ni < 4; ni++){
        int col = nb + wc + ni*16 + lm;
        #pragma unroll
        for (int i = 0; i < 4; i++)
          Obuf[(size_t)(rbase + i) * DIM + col] = f2bf(acc[mi][ni][i]);
      }
    }
  } else {
    #pragma unroll
    for (int mi = 0; mi < 4; mi++){
      int rbase = grb + wr + mi*16 + lg*4;
      #pragma unroll
      for (int ni = 0; ni < 4; ni++){
        int col = nb + wc + ni*16 + lm;
        #pragma unroll
        for (int i = 0; i < 4; i++){
          size_t p = (size_t)(rbase + i) * DIM + col;
          Obuf[p] = f2bf(bf2f(Obuf[p]) + acc[mi][ni][i]);   // block-exclusive, no atomic needed
        }
      }
    }
  }
}

// Tier A combine: out[t] = Obuf[slot0] + Obuf[slot1] + g0*b2[e0] + g1*b2[e1]
__global__ __launch_bounds__(192) void k_combine(
    const u16* __restrict__ Obuf, const int* __restrict__ tSlot,
    const int* __restrict__ tE, const float* __restrict__ tG,
    const float* __restrict__ b2, float* __restrict__ out)
{
  int t = blockIdx.x;
  int l = threadIdx.x;            // 192 threads, 4 cols each
  int s0 = tSlot[2*t], s1 = tSlot[2*t+1];
  int e0 = tE[2*t], e1 = tE[2*t+1];
  float g0 = tG[2*t], g1 = tG[2*t+1];
  int c = l * 4;
  ushort4 a = *(const ushort4*)(Obuf + (size_t)s0 * DIM + c);
  ushort4 b = *(const ushort4*)(Obuf + (size_t)s1 * DIM + c);
  float4 bA = *(const float4*)(b2 + (size_t)e0 * DIM + c);
  float4 bB = *(const float4*)(b2 + (size_t)e1 * DIM + c);
  float4 r;
  r.x = bf2f(a.x) + bf2f(b.x) + g0 * bA.x + g1 * bB.x;
  r.y = bf2f(a.y) + bf2f(b.y) + g0 * bA.y + g1 * bB.y;
  r.z = bf2f(a.z) + bf2f(b.z) + g0 * bA.z + g1 * bB.z;
  r.w = bf2f(a.w) + bf2f(b.w) + g0 * bA.w + g1 * bB.w;
  *(float4*)(out + (size_t)t * DIM + c) = r;
}

// ================= launch =================
extern "C" void kernel_launch(void* const* d_in, const int* in_sizes, int n_in,
                              void* d_out, int out_size, void* d_ws, size_t ws_size,
                              hipStream_t stream)
{
  const float* x  = (const float*)d_in[0];
  const float* Wg = (const float*)d_in[1];
  const float* bg = (const float*)d_in[2];
  const float* W1 = (const float*)d_in[3];
  const float* b1 = (const float*)d_in[4];
  const float* W2 = (const float*)d_in[5];
  const float* b2 = (const float*)d_in[6];
  float* out = (float*)d_out;
  char* ws = (char*)d_ws;

  u16*   W1t        = (u16*)(ws + O_W1T);
  u16*   W2t        = (u16*)(ws + O_W2T);
  u16*   Xbf        = (u16*)(ws + O_XBF);
  u16*   Hbuf       = (u16*)(ws + O_HBF);
  u16*   Obuf       = (u16*)(ws + O_OBF);
  int*   slot_token = (int*)(ws + O_STK);
  float* slot_gate  = (float*)(ws + O_SGT);
  int*   tE         = (int*)(ws + O_TE);
  float* tG         = (float*)(ws + O_TG);
  int*   tSlot      = (int*)(ws + O_TS);
  int*   meta       = (int*)(ws + O_MET);
  int*   counts = meta;
  int*   fill   = meta + 8;
  int*   offs   = meta + 16;

  const bool tierA = (ws_size >= WS_TIER_A);

  // zero slot arrays (pad rows => token 0, gate 0) and counts/fill
  hipMemsetAsync(ws + O_STK, 0, O_TE - O_STK, stream);
  hipMemsetAsync(ws + O_MET, 0, 128, stream);

  k_transposeW1<<<dim3(HH/32, DIM/32, NE), dim3(32, 8), 0, stream>>>(W1, W1t);
  k_transposeW2<<<dim3(DIM/32, HH/32, NE), dim3(32, 8), 0, stream>>>(W2, W2t);
  k_castX<<<3072, 256, 0, stream>>>(x, Xbf);

  k_router<<<T_TOK/4, 256, 0, stream>>>(x, Wg, bg, tE, tG);
  k_count<<<32, 256, 0, stream>>>(tE, counts);
  k_scan<<<1, 1, 0, stream>>>(counts, offs);
  k_scatter<<<T_TOK/256, 256, 0, stream>>>(tE, tG, offs, fill, slot_token, slot_gate, tSlot);
  if (!tierA)
    k_outinit<<<T_TOK, 256, 0, stream>>>(tE, tG, b2, out);

  for (int c = 0; c < NCH; c++){
    k_gemm1<<<dim3(CH/128, 128, NE), 256, 0, stream>>>(Xbf, W1t, b1, slot_token, slot_gate, offs, Hbuf, c * CH);
    int mode = tierA ? (c == 0 ? 1 : 2) : 0;
    k_gemm2<<<dim3(DIM/128, 128, NE), 256, 0, stream>>>(Hbuf, W2t, slot_token, offs, out, Obuf, c * CH, mode);
  }
  if (tierA)
    k_combine<<<T_TOK, 192, 0, stream>>>(Obuf, tSlot, tE, tG, b2, out);
}

// Round 4
// 642.997 us; speedup vs baseline: 2.0079x; 1.0651x over previous
//
#include <hip/hip_runtime.h>
#include <stdint.h>

typedef unsigned short u16;
typedef __attribute__((ext_vector_type(8))) short v8s;   // 8 x bf16 (as raw shorts)
typedef __attribute__((ext_vector_type(4))) float v4f;   // MFMA accumulator

#define T_TOK 16384
#define DIM   768
#define NE    8
#define HH    3072
#define CH    1536      // H chunk
#define NCH   2
#define MCAP  33792     // max padded slot rows (32768 + 8*127, rounded to 128)

// ---- workspace layout (bytes) ----
#define O_W1T 0u            // 37,748,736  bf16 [E][H][D]
#define O_W2T 37748736u     // 37,748,736  bf16 [E][D][H]
#define O_XBF 75497472u     // 25,165,824  bf16 [T][D]
#define O_STK 100663296u    // MCAP*4 slot_token
#define O_SGT 100798464u    // MCAP*4 slot_gate
#define O_TE  100933632u    // T*2*4 expert ids
#define O_TG  101064704u    // T*2*4 gates
#define O_TS  101195776u    // T*2*4 token->slot
#define O_MET 101326848u    // counts/fill/offs
#define O_HBF 101327104u    // MCAP*CH*2 = 103,809,024
#define O_OBF 205136128u    // MCAP*DIM*2 = 51,904,512 (Tier A only)
#define WS_TIER_A 257040640ull

__device__ __forceinline__ u16 f2bf(float f){
  uint32_t u = __float_as_uint(f);
  uint32_t r = (u + 0x7fffu + ((u >> 16) & 1u)) >> 16;  // RNE
  return (u16)r;
}
__device__ __forceinline__ float bf2f(u16 v){
  return __uint_as_float(((uint32_t)v) << 16);
}
// async global->LDS, 16B per lane; LDS dest = wave-uniform base + lane*16
__device__ __forceinline__ void gll16(const u16* g, u16* l){
  __builtin_amdgcn_global_load_lds((const __attribute__((address_space(1))) uint32_t*)g,
                                   (__attribute__((address_space(3))) uint32_t*)l, 16, 0, 0);
}

// ================= casts / transposes =================
__global__ void k_transposeW1(const float* __restrict__ W1, u16* __restrict__ W1t){
  __shared__ float tile[32][33];
  int e = blockIdx.z;
  int h0 = blockIdx.x * 32, d0 = blockIdx.y * 32;
  const float* src = W1 + (size_t)e * DIM * HH;     // [D][H]
  u16* dst = W1t + (size_t)e * HH * DIM;            // [H][D]
  int tx = threadIdx.x, ty = threadIdx.y;
  #pragma unroll
  for (int j = 0; j < 4; j++)
    tile[ty + 8*j][tx] = src[(size_t)(d0 + ty + 8*j) * HH + h0 + tx];
  __syncthreads();
  #pragma unroll
  for (int j = 0; j < 4; j++)
    dst[(size_t)(h0 + ty + 8*j) * DIM + d0 + tx] = f2bf(tile[tx][ty + 8*j]);
}

__global__ void k_transposeW2(const float* __restrict__ W2, u16* __restrict__ W2t){
  __shared__ float tile[32][33];
  int e = blockIdx.z;
  int d0 = blockIdx.x * 32, h0 = blockIdx.y * 32;
  const float* src = W2 + (size_t)e * HH * DIM;     // [H][D]
  u16* dst = W2t + (size_t)e * DIM * HH;            // [D][H]
  int tx = threadIdx.x, ty = threadIdx.y;
  #pragma unroll
  for (int j = 0; j < 4; j++)
    tile[ty + 8*j][tx] = src[(size_t)(h0 + ty + 8*j) * DIM + d0 + tx];
  __syncthreads();
  #pragma unroll
  for (int j = 0; j < 4; j++)
    dst[(size_t)(d0 + ty + 8*j) * HH + h0 + tx] = f2bf(tile[tx][ty + 8*j]);
}

__global__ void k_castX(const float* __restrict__ x, u16* __restrict__ Xbf){
  int i = blockIdx.x * blockDim.x + threadIdx.x;
  const int n4 = T_TOK * DIM / 4;
  for (int idx = i; idx < n4; idx += gridDim.x * blockDim.x){
    float4 v = ((const float4*)x)[idx];
    ushort4 o;
    o.x = f2bf(v.x); o.y = f2bf(v.y); o.z = f2bf(v.z); o.w = f2bf(v.w);
    ((ushort4*)Xbf)[idx] = o;
  }
}

// ================= router (no atomics) =================
__global__ __launch_bounds__(256) void k_router(
    const float* __restrict__ x, const float* __restrict__ Wg, const float* __restrict__ bg,
    int* __restrict__ tE, float* __restrict__ tG){
  int t = blockIdx.x * 4 + (threadIdx.x >> 6);
  int l = threadIdx.x & 63;
  const float* xr = x + (size_t)t * DIM;
  float acc[NE];
  #pragma unroll
  for (int e = 0; e < NE; e++) acc[e] = 0.f;
  #pragma unroll
  for (int j = 0; j < DIM / 64; j++){
    int c = l + 64 * j;
    float xv = xr[c];
    const float4* wr4 = (const float4*)(Wg + (size_t)c * NE);
    float4 w0 = wr4[0], w1 = wr4[1];
    acc[0] += xv * w0.x; acc[1] += xv * w0.y; acc[2] += xv * w0.z; acc[3] += xv * w0.w;
    acc[4] += xv * w1.x; acc[5] += xv * w1.y; acc[6] += xv * w1.z; acc[7] += xv * w1.w;
  }
  #pragma unroll
  for (int off = 32; off; off >>= 1)
    #pragma unroll
    for (int e = 0; e < NE; e++) acc[e] += __shfl_xor(acc[e], off, 64);

  if (l == 0){
    float lgt[NE];
    #pragma unroll
    for (int e = 0; e < NE; e++) lgt[e] = acc[e] + bg[e];

    int i0 = 0; float v0 = lgt[0];
    #pragma unroll
    for (int e = 1; e < NE; e++) if (lgt[e] > v0){ v0 = lgt[e]; i0 = e; }
    int i1 = -1; float v1 = -1e30f;
    #pragma unroll
    for (int e = 0; e < NE; e++) if (e != i0 && lgt[e] > v1){ v1 = lgt[e]; i1 = e; }

    float ed = expf(v1 - v0);            // <= 1
    float g1 = ed / (1.f + ed);
    float g0 = 1.f / (1.f + ed);

    tE[2*t] = i0; tE[2*t+1] = i1;
    tG[2*t] = g0; tG[2*t+1] = g1;
  }
}

// ================= count (register histogram) =================
__global__ __launch_bounds__(256) void k_count(const int* __restrict__ tE, int* __restrict__ counts){
  int i = blockIdx.x * blockDim.x + threadIdx.x;   // 32 x 256
  int c[NE];
  #pragma unroll
  for (int e = 0; e < NE; e++) c[e] = 0;
  for (int j = i; j < 2 * T_TOK; j += 32 * 256){
    int v = tE[j];
    #pragma unroll
    for (int e = 0; e < NE; e++) c[e] += (v == e);
  }
  #pragma unroll
  for (int off = 32; off; off >>= 1)
    #pragma unroll
    for (int e = 0; e < NE; e++) c[e] += __shfl_xor(c[e], off, 64);
  if ((threadIdx.x & 63) == 0){
    #pragma unroll
    for (int e = 0; e < NE; e++) atomicAdd(&counts[e], c[e]);
  }
}

__global__ void k_scan(const int* __restrict__ counts, int* __restrict__ offs){
  if (threadIdx.x == 0){
    int o = 0;
    for (int e = 0; e < NE; e++){ offs[e] = o; o += (counts[e] + 127) & ~127; }
    offs[NE] = o;
  }
}

// ================= scatter (ballot-rank, 8 atomics/block) =================
__global__ __launch_bounds__(256) void k_scatter(
    const int* __restrict__ tE, const float* __restrict__ tG,
    const int* __restrict__ offs, int* __restrict__ fill,
    int* __restrict__ slot_token, float* __restrict__ slot_gate, int* __restrict__ tSlot){
  int t = blockIdx.x * 256 + threadIdx.x;
  int lane = threadIdx.x & 63, w = threadIdx.x >> 6;
  int e0 = tE[2*t], e1 = tE[2*t+1];
  float g0 = tG[2*t], g1 = tG[2*t+1];

  __shared__ int wcnt[4][NE];
  __shared__ int woff[4][NE];
  __shared__ int bbase[NE];

  uint64_t below = (1ull << lane) - 1ull;
  int rank0 = 0, rank1 = 0;
  #pragma unroll
  for (int e = 0; e < NE; e++){
    uint64_t m0 = __ballot(e0 == e);
    uint64_t m1 = __ballot(e1 == e);
    int c0 = __popcll(m0);
    if (e0 == e) rank0 = __popcll(m0 & below);
    if (e1 == e) rank1 = c0 + __popcll(m1 & below);
    if (lane == 0) wcnt[w][e] = c0 + __popcll(m1);
  }
  __syncthreads();
  if (threadIdx.x < NE){
    int e = threadIdx.x;
    int s = 0;
    #pragma unroll
    for (int ww = 0; ww < 4; ww++){ woff[ww][e] = s; s += wcnt[ww][e]; }
    bbase[e] = atomicAdd(&fill[e], s);
  }
  __syncthreads();
  int p0 = offs[e0] + bbase[e0] + woff[w][e0] + rank0;
  slot_token[p0] = t; slot_gate[p0] = g0; tSlot[2*t] = p0;
  int p1 = offs[e1] + bbase[e1] + woff[w][e1] + rank1;
  slot_token[p1] = t; slot_gate[p1] = g1; tSlot[2*t+1] = p1;
}

// Tier B only: out init = g0*b2[e0] + g1*b2[e1]
__global__ void k_outinit(const int* __restrict__ tE, const float* __restrict__ tG,
                          const float* __restrict__ b2, float* __restrict__ out){
  int t = blockIdx.x;
  int e0 = tE[2*t], e1 = tE[2*t+1];
  float g0 = tG[2*t], g1 = tG[2*t+1];
  const float* r0 = b2 + (size_t)e0 * DIM;
  const float* r1 = b2 + (size_t)e1 * DIM;
  float* o = out + (size_t)t * DIM;
  #pragma unroll
  for (int j = 0; j < DIM / 256; j++){
    int c = threadIdx.x + 256 * j;
    o[c] = g0 * r0[c] + g1 * r1[c];
  }
}

// ============ grouped GEMMs: m97 structure + bijective XCD swizzle (T1/m204) ============
// GEMM1: H[slot][h] = relu(X[token] @ W1[e] + b1[e]) * gate   (K = DIM = 768)
// 1D grid 12288 = NE * 128(mt) * 12(nt), nt innermost; chunked swizzle keeps the
// 12 nt-siblings (sharing the A-tile) on one XCD -> A re-reads become L2 hits.
__global__ __launch_bounds__(256) void k_gemm1(
    const u16* __restrict__ Xbf, const u16* __restrict__ W1t, const float* __restrict__ b1,
    const int* __restrict__ slot_token, const float* __restrict__ slot_gate,
    const int* __restrict__ offs, u16* __restrict__ Hbuf, int cbase)
{
  const int NWG = NE * 128 * (CH / 128);      // 12288
  const int CPX = NWG / 8;
  int bid = blockIdx.x;
  int swz = (bid & 7) * CPX + (bid >> 3);
  int e  = swz / (128 * (CH / 128));
  int rem = swz % (128 * (CH / 128));
  int mt = rem / (CH / 128);
  int nt = rem % (CH / 128);

  int mbase = offs[e];
  int pc = offs[e+1] - mbase;
  if (mt * 128 >= pc) return;
  int grb = mbase + mt * 128;
  int nb = nt * 128;              // col base within chunk
  int habs = cbase + nb;          // absolute h col base

  __shared__ u16 As[128 * 32];    // linear: row stride 32 elems (64B) — required by global_load_lds
  __shared__ u16 Bs[128 * 32];

  int tid = threadIdx.x;
  int w = tid >> 6, lane = tid & 63;
  int lrow = lane >> 2, lu = lane & 3;          // 16 rows x 4 x 16B per wave-call
  int r0 = w * 32 + lrow, r1 = r0 + 16;

  const u16* ga0 = Xbf + (size_t)slot_token[grb + r0] * DIM + lu * 8;
  const u16* ga1 = Xbf + (size_t)slot_token[grb + r1] * DIM + lu * 8;
  const u16* gb0 = W1t + ((size_t)e * HH + habs + r0) * DIM + lu * 8;
  const u16* gb1 = W1t + ((size_t)e * HH + habs + r1) * DIM + lu * 8;
  u16* lA0 = &As[(w * 32) * 32];
  u16* lA1 = &As[(w * 32 + 16) * 32];
  u16* lB0 = &Bs[(w * 32) * 32];
  u16* lB1 = &Bs[(w * 32 + 16) * 32];

  int lm = lane & 15, lg = lane >> 4;
  int wr = (w >> 1) * 64, wc = (w & 1) * 64;
  const u16* rA[4]; const u16* rB[4];
  #pragma unroll
  for (int mi = 0; mi < 4; mi++) rA[mi] = &As[(wr + mi*16 + lm) * 32 + lg * 8];
  #pragma unroll
  for (int ni = 0; ni < 4; ni++) rB[ni] = &Bs[(wc + ni*16 + lm) * 32 + lg * 8];

  v4f acc[4][4];
  #pragma unroll
  for (int mi = 0; mi < 4; mi++)
    #pragma unroll
    for (int ni = 0; ni < 4; ni++) acc[mi][ni] = 0.f;

  const int nk = DIM / 32;  // 24
  for (int kb = 0; kb < nk; ++kb){
    __syncthreads();                       // prev reads done before DMA overwrite
    int o = kb * 32;
    gll16(ga0 + o, lA0); gll16(ga1 + o, lA1);
    gll16(gb0 + o, lB0); gll16(gb1 + o, lB1);
    __syncthreads();                       // compiler drains vmcnt(0) before barrier
    v8s af[4], bb[4];
    #pragma unroll
    for (int mi = 0; mi < 4; mi++) af[mi] = *(const v8s*)rA[mi];
    #pragma unroll
    for (int ni = 0; ni < 4; ni++) bb[ni] = *(const v8s*)rB[ni];
    #pragma unroll
    for (int mi = 0; mi < 4; mi++)
      #pragma unroll
      for (int ni = 0; ni < 4; ni++)
        acc[mi][ni] = __builtin_amdgcn_mfma_f32_16x16x32_bf16(af[mi], bb[ni], acc[mi][ni], 0, 0, 0);
  }

  float b1v[4];
  #pragma unroll
  for (int ni = 0; ni < 4; ni++) b1v[ni] = b1[(size_t)e * HH + habs + wc + ni*16 + lm];
  #pragma unroll
  for (int mi = 0; mi < 4; mi++){
    int rbase = grb + wr + mi*16 + lg*4;
    float g[4];
    #pragma unroll
    for (int i = 0; i < 4; i++) g[i] = slot_gate[rbase + i];
    #pragma unroll
    for (int ni = 0; ni < 4; ni++){
      int col = nb + wc + ni*16 + lm;
      #pragma unroll
      for (int i = 0; i < 4; i++){
        float v = acc[mi][ni][i] + b1v[ni];
        v = fmaxf(v, 0.f) * g[i];
        Hbuf[(size_t)(rbase + i) * CH + col] = f2bf(v);
      }
    }
  }
}

// GEMM2: Oslot[slot][d] (+)= H[slot] @ W2[e][chunk]    (K = CH)
// 1D grid 6144 = NE * 128(mt) * 6(nt), nt innermost, same swizzle.
// mode 0: atomic-add into out[token][d] (Tier B)
// mode 1: store to Obuf (first chunk, Tier A); mode 2: non-atomic RMW add (later chunks)
__global__ __launch_bounds__(256) void k_gemm2(
    const u16* __restrict__ Hbuf, const u16* __restrict__ W2t,
    const int* __restrict__ slot_token, const int* __restrict__ offs,
    float* __restrict__ out, u16* __restrict__ Obuf, int cbase, int mode)
{
  const int NWG = NE * 128 * (DIM / 128);     // 6144
  const int CPX = NWG / 8;
  int bid = blockIdx.x;
  int swz = (bid & 7) * CPX + (bid >> 3);
  int e  = swz / (128 * (DIM / 128));
  int rem = swz % (128 * (DIM / 128));
  int mt = rem / (DIM / 128);
  int nt = rem % (DIM / 128);

  int mbase = offs[e];
  int pc = offs[e+1] - mbase;
  if (mt * 128 >= pc) return;
  int grb = mbase + mt * 128;
  int nb = nt * 128;              // d col base

  __shared__ u16 As[128 * 32];
  __shared__ u16 Bs[128 * 32];

  int tid = threadIdx.x;
  int w = tid >> 6, lane = tid & 63;
  int lrow = lane >> 2, lu = lane & 3;
  int r0 = w * 32 + lrow, r1 = r0 + 16;

  const u16* ga0 = Hbuf + (size_t)(grb + r0) * CH + lu * 8;
  const u16* ga1 = Hbuf + (size_t)(grb + r1) * CH + lu * 8;
  const u16* gb0 = W2t + ((size_t)e * DIM + nb + r0) * HH + cbase + lu * 8;
  const u16* gb1 = W2t + ((size_t)e * DIM + nb + r1) * HH + cbase + lu * 8;
  u16* lA0 = &As[(w * 32) * 32];
  u16* lA1 = &As[(w * 32 + 16) * 32];
  u16* lB0 = &Bs[(w * 32) * 32];
  u16* lB1 = &Bs[(w * 32 + 16) * 32];

  int lm = lane & 15, lg = lane >> 4;
  int wr = (w >> 1) * 64, wc = (w & 1) * 64;
  const u16* rA[4]; const u16* rB[4];
  #pragma unroll
  for (int mi = 0; mi < 4; mi++) rA[mi] = &As[(wr + mi*16 + lm) * 32 + lg * 8];
  #pragma unroll
  for (int ni = 0; ni < 4; ni++) rB[ni] = &Bs[(wc + ni*16 + lm) * 32 + lg * 8];

  v4f acc[4][4];
  #pragma unroll
  for (int mi = 0; mi < 4; mi++)
    #pragma unroll
    for (int ni = 0; ni < 4; ni++) acc[mi][ni] = 0.f;

  const int nk = CH / 32;  // 48
  for (int kb = 0; kb < nk; ++kb){
    __syncthreads();
    int o = kb * 32;
    gll16(ga0 + o, lA0); gll16(ga1 + o, lA1);
    gll16(gb0 + o, lB0); gll16(gb1 + o, lB1);
    __syncthreads();
    v8s af[4], bb[4];
    #pragma unroll
    for (int mi = 0; mi < 4; mi++) af[mi] = *(const v8s*)rA[mi];
    #pragma unroll
    for (int ni = 0; ni < 4; ni++) bb[ni] = *(const v8s*)rB[ni];
    #pragma unroll
    for (int mi = 0; mi < 4; mi++)
      #pragma unroll
      for (int ni = 0; ni < 4; ni++)
        acc[mi][ni] = __builtin_amdgcn_mfma_f32_16x16x32_bf16(af[mi], bb[ni], acc[mi][ni], 0, 0, 0);
  }

  if (mode == 0){
    #pragma unroll
    for (int mi = 0; mi < 4; mi++){
      int rbase = grb + wr + mi*16 + lg*4;
      int tok[4];
      #pragma unroll
      for (int i = 0; i < 4; i++) tok[i] = slot_token[rbase + i];
      #pragma unroll
      for (int ni = 0; ni < 4; ni++){
        int col = nb + wc + ni*16 + lm;
        #pragma unroll
        for (int i = 0; i < 4; i++)
          unsafeAtomicAdd(&out[(size_t)tok[i] * DIM + col], acc[mi][ni][i]);
      }
    }
  } else if (mode == 1){
    #pragma unroll
    for (int mi = 0; mi < 4; mi++){
      int rbase = grb + wr + mi*16 + lg*4;
      #pragma unroll
      for (int ni = 0; ni < 4; ni++){
        int col = nb + wc + ni*16 + lm;
        #pragma unroll
        for (int i = 0; i < 4; i++)
          Obuf[(size_t)(rbase + i) * DIM + col] = f2bf(acc[mi][ni][i]);
      }
    }
  } else {
    #pragma unroll
    for (int mi = 0; mi < 4; mi++){
      int rbase = grb + wr + mi*16 + lg*4;
      #pragma unroll
      for (int ni = 0; ni < 4; ni++){
        int col = nb + wc + ni*16 + lm;
        #pragma unroll
        for (int i = 0; i < 4; i++){
          size_t p = (size_t)(rbase + i) * DIM + col;
          Obuf[p] = f2bf(bf2f(Obuf[p]) + acc[mi][ni][i]);   // block-exclusive, no atomic needed
        }
      }
    }
  }
}

// Tier A combine: out[t] = Obuf[slot0] + Obuf[slot1] + g0*b2[e0] + g1*b2[e1]
__global__ __launch_bounds__(192) void k_combine(
    const u16* __restrict__ Obuf, const int* __restrict__ tSlot,
    const int* __restrict__ tE, const float* __restrict__ tG,
    const float* __restrict__ b2, float* __restrict__ out)
{
  int t = blockIdx.x;
  int l = threadIdx.x;            // 192 threads, 4 cols each
  int s0 = tSlot[2*t], s1 = tSlot[2*t+1];
  int e0 = tE[2*t], e1 = tE[2*t+1];
  float g0 = tG[2*t], g1 = tG[2*t+1];
  int c = l * 4;
  ushort4 a = *(const ushort4*)(Obuf + (size_t)s0 * DIM + c);
  ushort4 b = *(const ushort4*)(Obuf + (size_t)s1 * DIM + c);
  float4 bA = *(const float4*)(b2 + (size_t)e0 * DIM + c);
  float4 bB = *(const float4*)(b2 + (size_t)e1 * DIM + c);
  float4 r;
  r.x = bf2f(a.x) + bf2f(b.x) + g0 * bA.x + g1 * bB.x;
  r.y = bf2f(a.y) + bf2f(b.y) + g0 * bA.y + g1 * bB.y;
  r.z = bf2f(a.z) + bf2f(b.z) + g0 * bA.z + g1 * bB.z;
  r.w = bf2f(a.w) + bf2f(b.w) + g0 * bA.w + g1 * bB.w;
  *(float4*)(out + (size_t)t * DIM + c) = r;
}

// ================= launch =================
extern "C" void kernel_launch(void* const* d_in, const int* in_sizes, int n_in,
                              void* d_out, int out_size, void* d_ws, size_t ws_size,
                              hipStream_t stream)
{
  const float* x  = (const float*)d_in[0];
  const float* Wg = (const float*)d_in[1];
  const float* bg = (const float*)d_in[2];
  const float* W1 = (const float*)d_in[3];
  const float* b1 = (const float*)d_in[4];
  const float* W2 = (const float*)d_in[5];
  const float* b2 = (const float*)d_in[6];
  float* out = (float*)d_out;
  char* ws = (char*)d_ws;

  u16*   W1t        = (u16*)(ws + O_W1T);
  u16*   W2t        = (u16*)(ws + O_W2T);
  u16*   Xbf        = (u16*)(ws + O_XBF);
  u16*   Hbuf       = (u16*)(ws + O_HBF);
  u16*   Obuf       = (u16*)(ws + O_OBF);
  int*   slot_token = (int*)(ws + O_STK);
  float* slot_gate  = (float*)(ws + O_SGT);
  int*   tE         = (int*)(ws + O_TE);
  float* tG         = (float*)(ws + O_TG);
  int*   tSlot      = (int*)(ws + O_TS);
  int*   meta       = (int*)(ws + O_MET);
  int*   counts = meta;
  int*   fill   = meta + 8;
  int*   offs   = meta + 16;

  const bool tierA = (ws_size >= WS_TIER_A);

  // zero slot arrays (pad rows => token 0, gate 0) and counts/fill
  hipMemsetAsync(ws + O_STK, 0, O_TE - O_STK, stream);
  hipMemsetAsync(ws + O_MET, 0, 128, stream);

  k_transposeW1<<<dim3(HH/32, DIM/32, NE), dim3(32, 8), 0, stream>>>(W1, W1t);
  k_transposeW2<<<dim3(DIM/32, HH/32, NE), dim3(32, 8), 0, stream>>>(W2, W2t);
  k_castX<<<3072, 256, 0, stream>>>(x, Xbf);

  k_router<<<T_TOK/4, 256, 0, stream>>>(x, Wg, bg, tE, tG);
  k_count<<<32, 256, 0, stream>>>(tE, counts);
  k_scan<<<1, 1, 0, stream>>>(counts, offs);
  k_scatter<<<T_TOK/256, 256, 0, stream>>>(tE, tG, offs, fill, slot_token, slot_gate, tSlot);
  if (!tierA)
    k_outinit<<<T_TOK, 256, 0, stream>>>(tE, tG, b2, out);

  for (int c = 0; c < NCH; c++){
    k_gemm1<<<NE * 128 * (CH/128), 256, 0, stream>>>(Xbf, W1t, b1, slot_token, slot_gate, offs, Hbuf, c * CH);
    int mode = tierA ? (c == 0 ? 1 : 2) : 0;
    k_gemm2<<<NE * 128 * (DIM/128), 256, 0, stream>>>(Hbuf, W2t, slot_token, offs, out, Obuf, c * CH, mode);
  }
  if (tierA)
    k_combine<<<T_TOK, 192, 0, stream>>>(Obuf, tSlot, tE, tG, b2, out);
}